// Round 10
// baseline (136.585 us; speedup 1.0000x reference)
//
#include <hip/hip_runtime.h>
#include <hip/hip_bf16.h>

#define B_ROWS 4096
#define DIN    768
#define DOUT   512
#define QDIM   64
#define H1C    32
#define H2C    64

// canonical fp32 weight block offsets (floats)
#define W_BP    0
#define W_WI1   512
#define W_BI1   544
#define W_WI2   576
#define W_BI2   2624
#define W_WO1   2688
#define W_BO1   2752
#define W_WO2   2816
#define W_BO2   35584
#define W_GAM   36096
#define W_BET   36608
#define W_TOT   37120

// ws layout (bytes)
#define WS_WPT  0          // 512*768*2  = 786432
#define WS_WO2T 786432     // 512*64*2   =  65536
#define WS_WW   851968     // 37120*4    = 148480

typedef short  short8_t  __attribute__((ext_vector_type(8)));
typedef __bf16 bf16x8_t  __attribute__((ext_vector_type(8)));
typedef float  f32x4_t   __attribute__((ext_vector_type(4)));

__device__ __forceinline__ float bf16bits_to_f32(unsigned short u) {
  return __builtin_bit_cast(float, ((unsigned int)u) << 16);
}
__device__ __forceinline__ unsigned short f32_to_bf16bits(float f) {
  return __builtin_bit_cast(unsigned short, __float2bfloat16(f));
}
__device__ __forceinline__ float ldf(const void* p, int i, bool isb) {
  if (isb) return bf16bits_to_f32(((const unsigned short*)p)[i]);
  return ((const float*)p)[i];
}
// per-wave dtype detect from x's first 64 words (verified: picks fp32 here)
__device__ __forceinline__ bool detect_bf16(const unsigned int* xw, int t) {
  const unsigned int w = xw[t & 63];
  const unsigned int e = (w >> 7) & 0xffu;
  const bool hit = (e >= 118u && e <= 127u);
  return __popcll(__ballot(hit)) >= 40;
}

// ---------- kernel 1: prep — wpT bf16, wo2T bf16, weights fp32 ----------
// blocks 0..383: wpT tiles; 384..415: wo2T tiles; 416..423: wW
__global__ __launch_bounds__(256) void k_prep(
    const void* __restrict__ x, const void* __restrict__ wp,
    const void* __restrict__ bp,
    const void* __restrict__ wi1, const void* __restrict__ bi1,
    const void* __restrict__ wi2, const void* __restrict__ bi2,
    const void* __restrict__ wo1, const void* __restrict__ bo1,
    const void* __restrict__ wo2, const void* __restrict__ bo2,
    const void* __restrict__ gamma, const void* __restrict__ beta,
    unsigned short* __restrict__ wpT,    // [512][768] bf16
    unsigned short* __restrict__ wo2T,   // [512][64]  bf16
    float* __restrict__ wW)
{
  const int t = threadIdx.x, b = blockIdx.x;
  const bool isb = detect_bf16((const unsigned int*)x, t);
  const int tx = t & 31, ty = t >> 5;

  if (b < 384) {
    __shared__ unsigned short tile[32][33];
    const int n0 = (b & 15) * 32, k0 = (b >> 4) * 32;
#pragma unroll
    for (int i = 0; i < 32; i += 8)
      tile[ty + i][tx] = f32_to_bf16bits(ldf(wp, (k0 + ty + i) * DOUT + n0 + tx, isb));
    __syncthreads();
#pragma unroll
    for (int i = 0; i < 32; i += 8)
      wpT[(size_t)(n0 + ty + i) * DIN + k0 + tx] = tile[tx][ty + i];
  } else if (b < 416) {
    __shared__ unsigned short tile[32][33];
    const int tb = b - 384;
    const int c0 = (tb & 15) * 32, g0 = (tb >> 4) * 32;
#pragma unroll
    for (int i = 0; i < 32; i += 8)
      tile[ty + i][tx] = f32_to_bf16bits(ldf(wo2, (g0 + ty + i) * DOUT + c0 + tx, isb));
    __syncthreads();
#pragma unroll
    for (int i = 0; i < 32; i += 8)
      wo2T[(size_t)(c0 + ty + i) * QDIM + g0 + tx] = tile[tx][ty + i];
  } else {
    for (int e = (b - 416) * 256 + t; e < W_TOT; e += 8 * 256) {
      float v;
      if      (e < W_WI1) v = ldf(bp,    e - W_BP,  isb);
      else if (e < W_BI1) v = ldf(wi1,   e - W_WI1, isb);
      else if (e < W_WI2) v = ldf(bi1,   e - W_BI1, isb);
      else if (e < W_BI2) v = ldf(wi2,   e - W_WI2, isb);
      else if (e < W_WO1) v = ldf(bi2,   e - W_BI2, isb);
      else if (e < W_BO1) v = ldf(wo1,   e - W_WO1, isb);
      else if (e < W_WO2) v = ldf(bo1,   e - W_BO1, isb);
      else if (e < W_BO2) v = ldf(wo2,   e - W_WO2, isb);
      else if (e < W_GAM) v = ldf(bo2,   e - W_BO2, isb);
      else if (e < W_BET) v = ldf(gamma, e - W_GAM, isb);
      else                v = ldf(beta,  e - W_BET, isb);
      wW[e] = v;
    }
  }
}

// ---------- kernel 2: fused GEMM + KAN tail + LN; 16 rows/block, 1024 threads ----------
__global__ __launch_bounds__(1024) void k_main(
    const void* __restrict__ x,              // [4096][768]
    const unsigned short* __restrict__ wpT,  // [512][768] bf16
    const unsigned short* __restrict__ wo2T, // [512][64]  bf16
    const float* __restrict__ wW,
    void* __restrict__ out)
{
  // LDS map (bytes):
  //  region0 [0,33024): As ushort[16][776] (GEMM) / sXp float[16][516] (tail)
  //  sS  @33024 f32[16][32]   sU @35072 f32[16][64]
  //  sTb @39168 bf16[16][72]  sRed @41472 f32[16][16][2]
  //  sStats @43520 f32[16][2] sW1 @43648 f32[32]  sB1 @43776 f32[32]
  __shared__ alignas(16) char smem[43904];
  unsigned short* As   = (unsigned short*)smem;
  float*          sXp  = (float*)smem;
  float*          sS   = (float*)(smem + 33024);
  float*          sU   = (float*)(smem + 35072);
  unsigned short* sTb  = (unsigned short*)(smem + 39168);
  float*          sRed = (float*)(smem + 41472);
  float*          sSt  = (float*)(smem + 43520);
  float*          sW1  = (float*)(smem + 43648);
  float*          sB1  = (float*)(smem + 43776);

  const int t    = threadIdx.x;
  const int wv   = t >> 6, lane = t & 63;
  const int lm   = lane & 15, quad = lane >> 4;
  const int b0   = blockIdx.x * 16;
  const bool isb = detect_bf16((const unsigned int*)x, t);

  // ---- stage A: 16 rows x 768 -> As bf16[16][776]; 3 chunks of 4 per thread ----
#pragma unroll
  for (int i = 0; i < 3; ++i) {
    const int c = i * 1024 + t;            // 0..3071
    const int row = c / 192, off = (c - row * 192) * 4;
    unsigned short a4[4];
    if (isb) {
      const uint2 v = *(const uint2*)((const unsigned short*)x + (size_t)(b0 + row) * DIN + off);
      *(uint2*)a4 = v;
    } else {
      const float4 f = *(const float4*)((const float*)x + (size_t)(b0 + row) * DIN + off);
      a4[0] = f32_to_bf16bits(f.x); a4[1] = f32_to_bf16bits(f.y);
      a4[2] = f32_to_bf16bits(f.z); a4[3] = f32_to_bf16bits(f.w);
    }
    *(uint2*)&As[row * 776 + off] = *(const uint2*)a4;
  }
  if (t < 32) { sW1[t] = wW[W_WI1 + t]; sB1[t] = wW[W_BI1 + t]; }

  // ---- B prefetch (kt=0,1) issued before the barrier ----
  const unsigned short* wb0 = wpT + (size_t)(wv * 32 + lm) * DIN + quad * 8;
  const unsigned short* wb1 = wb0 + 16 * DIN;
  short8_t c0 = *(const short8_t*)wb0;
  short8_t c1 = *(const short8_t*)wb1;
  short8_t n0 = *(const short8_t*)(wb0 + 32);
  short8_t n1 = *(const short8_t*)(wb1 + 32);
  __syncthreads();

  // ---- K-loop: 24 iters, 2 chains/wave, depth-2 prefetch, no barriers ----
  f32x4_t acc0 = {}, acc1 = {};
#pragma unroll
  for (int kt = 0; kt < 24; ++kt) {
    const short8_t f0 = *(const short8_t*)(wb0 + (kt + 2) * 32);  // overruns land in wo2T (valid)
    const short8_t f1 = *(const short8_t*)(wb1 + (kt + 2) * 32);
    const short8_t av = *(const short8_t*)&As[lm * 776 + kt * 32 + quad * 8];
    const bf16x8_t af = __builtin_bit_cast(bf16x8_t, av);
    acc0 = __builtin_amdgcn_mfma_f32_16x16x32_bf16(af, __builtin_bit_cast(bf16x8_t, c0), acc0, 0, 0, 0);
    acc1 = __builtin_amdgcn_mfma_f32_16x16x32_bf16(af, __builtin_bit_cast(bf16x8_t, c1), acc1, 0, 0, 0);
    c0 = n0; c1 = n1; n0 = f0; n1 = f1;
  }
  __syncthreads();   // As reads done before sXp overlays

  // ---- epilogue: C layout col=lm, row=quad*4+i (verified R7) ----
  {
    const int ca = wv * 32 + lm, cb = ca + 16;
    const float bpa = wW[W_BP + ca], bpb = wW[W_BP + cb];
#pragma unroll
    for (int i = 0; i < 4; ++i) {
      sXp[(quad * 4 + i) * 516 + ca] = acc0[i] + bpa;
      sXp[(quad * 4 + i) * 516 + cb] = acc1[i] + bpb;
    }
  }
  __syncthreads();

  // ---- phase S: wave wv = row; lane: cg=lane&31 -> 16 cols, hg=lane>>5 -> 16 h ----
  {
    const int r = wv, cg = lane & 31, hg = lane >> 5;
    const float* row = &sXp[r * 516 + cg * 16];
    float xc[16];
#pragma unroll
    for (int j = 0; j < 4; ++j) {
      const float4 v = *(const float4*)&row[j * 4];
      xc[j*4+0] = v.x; xc[j*4+1] = v.y; xc[j*4+2] = v.z; xc[j*4+3] = v.w;
    }
    float S16[16];
#pragma unroll
    for (int j = 0; j < 16; ++j) {
      const float w = sW1[hg * 16 + j], bb = sB1[hg * 16 + j];
      float a = 0.f;
#pragma unroll
      for (int c = 0; c < 16; ++c) a += fmaxf(fmaf(xc[c], w, bb), 0.f);
      S16[j] = a;
    }
#pragma unroll
    for (int off = 1; off < 32; off <<= 1)
#pragma unroll
      for (int j = 0; j < 16; ++j) S16[j] += __shfl_xor(S16[j], off);
    if (cg == 0) {
#pragma unroll
      for (int j = 0; j < 16; ++j) sS[r * 32 + hg * 16 + j] = S16[j];
    }
  }
  __syncthreads();

  // ---- phase u: thread t -> (r=t>>6, q=t&63) ----
  {
    const int r = t >> 6, q = t & 63;
    float a = 0.f;
#pragma unroll
    for (int h4 = 0; h4 < 32; h4 += 4) {
      const float4 s4 = *(const float4*)&sS[r * 32 + h4];
      a = fmaf(s4.x, wW[W_WI2 + (h4 + 0) * QDIM + q], a);
      a = fmaf(s4.y, wW[W_WI2 + (h4 + 1) * QDIM + q], a);
      a = fmaf(s4.z, wW[W_WI2 + (h4 + 2) * QDIM + q], a);
      a = fmaf(s4.w, wW[W_WI2 + (h4 + 3) * QDIM + q], a);
    }
    sU[t] = a + 512.f * wW[W_BI2 + q];
  }
  __syncthreads();

  // ---- phase T: thread t -> (r=t>>6, g=t&63); T stored bf16 for MFMA ----
  {
    const int r = t >> 6, g = t & 63;
    const float w = wW[W_WO1 + g], bb = wW[W_BO1 + g];
    float a = 0.f;
#pragma unroll
    for (int q = 0; q < QDIM; q += 4) {
      const float4 v = *(const float4*)&sU[r * 64 + q];
      a += fmaxf(fmaf(v.x, w, bb), 0.f);
      a += fmaxf(fmaf(v.y, w, bb), 0.f);
      a += fmaxf(fmaf(v.z, w, bb), 0.f);
      a += fmaxf(fmaf(v.w, w, bb), 0.f);
    }
    sTb[r * 72 + g] = f32_to_bf16bits(a);
  }
  __syncthreads();

  // ---- summed via MFMA: D[16r][32c per wave] = T[16][64] @ wo2T^T ----
  f32x4_t sa0 = {}, sa1 = {};
  {
    const unsigned short* wcol0 = wo2T + (size_t)(wv * 32 + lm) * QDIM + quad * 8;
    const unsigned short* wcol1 = wcol0 + 16 * QDIM;
#pragma unroll
    for (int kt = 0; kt < 2; ++kt) {
      const short8_t aT = *(const short8_t*)&sTb[lm * 72 + kt * 32 + quad * 8];
      const bf16x8_t aTf = __builtin_bit_cast(bf16x8_t, aT);
      const short8_t bW0 = *(const short8_t*)(wcol0 + kt * 32);
      const short8_t bW1 = *(const short8_t*)(wcol1 + kt * 32);
      sa0 = __builtin_amdgcn_mfma_f32_16x16x32_bf16(aTf, __builtin_bit_cast(bf16x8_t, bW0), sa0, 0, 0, 0);
      sa1 = __builtin_amdgcn_mfma_f32_16x16x32_bf16(aTf, __builtin_bit_cast(bf16x8_t, bW1), sa1, 0, 0, 0);
    }
  }
  const int colA = wv * 32 + lm, colB = colA + 16;
  {
    const float bzA = 64.f * wW[W_BO2 + colA];
    const float bzB = 64.f * wW[W_BO2 + colB];
#pragma unroll
    for (int i = 0; i < 4; ++i) { sa0[i] += bzA; sa1[i] += bzB; }
  }
  // per-row stats: butterfly over the 16 lm-lanes, rows = quad*4+i
  {
    float pr[4], prs[4];
#pragma unroll
    for (int i = 0; i < 4; ++i) {
      pr[i]  = sa0[i] + sa1[i];
      prs[i] = sa0[i] * sa0[i] + sa1[i] * sa1[i];
    }
#pragma unroll
    for (int off = 1; off < 16; off <<= 1)
#pragma unroll
      for (int i = 0; i < 4; ++i) {
        pr[i]  += __shfl_xor(pr[i],  off);
        prs[i] += __shfl_xor(prs[i], off);
      }
    if (lm == 0) {
#pragma unroll
      for (int i = 0; i < 4; ++i) {
        sRed[(wv * 16 + quad * 4 + i) * 2 + 0] = pr[i];
        sRed[(wv * 16 + quad * 4 + i) * 2 + 1] = prs[i];
      }
    }
  }
  __syncthreads();
  if (t < 16) {
    float sm = 0.f, sq = 0.f;
#pragma unroll
    for (int w = 0; w < 16; ++w) {
      sm += sRed[(w * 16 + t) * 2 + 0];
      sq += sRed[(w * 16 + t) * 2 + 1];
    }
    const float mu  = sm * (1.f / 512.f);
    const float var = fmaxf(sq * (1.f / 512.f) - mu * mu, 0.f);
    sSt[t * 2 + 0] = mu;
    sSt[t * 2 + 1] = rsqrtf(var + 1e-5f);
  }
  __syncthreads();

  // ---- LN + store from D-regs ----
  {
    const float gA = wW[W_GAM + colA], bA = wW[W_BET + colA];
    const float gB = wW[W_GAM + colB], bB = wW[W_BET + colB];
#pragma unroll
    for (int i = 0; i < 4; ++i) {
      const int r = quad * 4 + i;
      const float mu = sSt[r * 2 + 0], rstd = sSt[r * 2 + 1];
      const float oA = (sa0[i] - mu) * rstd * gA + bA;
      const float oB = (sa1[i] - mu) * rstd * gB + bB;
      if (isb) {
        ((unsigned short*)out)[(size_t)(b0 + r) * DOUT + colA] = f32_to_bf16bits(oA);
        ((unsigned short*)out)[(size_t)(b0 + r) * DOUT + colB] = f32_to_bf16bits(oB);
      } else {
        ((float*)out)[(size_t)(b0 + r) * DOUT + colA] = oA;
        ((float*)out)[(size_t)(b0 + r) * DOUT + colB] = oB;
      }
    }
  }
}

extern "C" void kernel_launch(void* const* d_in, const int* in_sizes, int n_in,
                              void* d_out, int out_size, void* d_ws, size_t ws_size,
                              hipStream_t stream) {
  char* ws = (char*)d_ws;
  unsigned short* wpT  = (unsigned short*)(ws + WS_WPT);
  unsigned short* wo2T = (unsigned short*)(ws + WS_WO2T);
  float*          wW   = (float*)(ws + WS_WW);

  k_prep<<<424, 256, 0, stream>>>(d_in[0], d_in[1], d_in[2], d_in[3], d_in[4],
                                  d_in[5], d_in[6], d_in[7], d_in[8], d_in[9],
                                  d_in[10], d_in[11], d_in[12], wpT, wo2T, wW);
  k_main<<<B_ROWS / 16, 1024, 0, stream>>>(d_in[0], wpT, wo2T, wW, d_out);
}

// Round 11
// 129.778 us; speedup vs baseline: 1.0525x; 1.0525x over previous
//
#include <hip/hip_runtime.h>
#include <hip/hip_bf16.h>

#define B_ROWS 4096
#define DIN    768
#define DOUT   512
#define QDIM   64
#define H1C    32
#define H2C    64

// canonical fp32 weight block offsets (floats)
#define W_BP    0
#define W_WI1   512
#define W_BI1   544
#define W_WI2   576
#define W_BI2   2624
#define W_WO1   2688
#define W_BO1   2752
#define W_WO2   2816
#define W_BO2   35584
#define W_GAM   36096
#define W_BET   36608
#define W_TOT   37120

// ws layout (bytes)
#define WS_WPT  0          // 512*768*2  = 786432
#define WS_WO2T 786432     // 512*64*2   =  65536  (also absorbs K-loop prefetch overrun)
#define WS_WW   851968     // 37120*4

typedef short  short8_t  __attribute__((ext_vector_type(8)));
typedef __bf16 bf16x8_t  __attribute__((ext_vector_type(8)));
typedef float  f32x4_t   __attribute__((ext_vector_type(4)));

__device__ __forceinline__ float bf16bits_to_f32(unsigned short u) {
  return __builtin_bit_cast(float, ((unsigned int)u) << 16);
}
__device__ __forceinline__ unsigned short f32_to_bf16bits(float f) {
  return __builtin_bit_cast(unsigned short, __float2bfloat16(f));
}
__device__ __forceinline__ float ldf(const void* p, int i, bool isb) {
  if (isb) return bf16bits_to_f32(((const unsigned short*)p)[i]);
  return ((const float*)p)[i];
}
// per-wave dtype detect from x's first 64 words (verified: picks fp32 here)
__device__ __forceinline__ bool detect_bf16(const unsigned int* xw, int t) {
  const unsigned int w = xw[t & 63];
  const unsigned int e = (w >> 7) & 0xffu;
  const bool hit = (e >= 118u && e <= 127u);
  return __popcll(__ballot(hit)) >= 40;
}

// ---------- kernel 1: prep — wpT bf16, wo2T bf16, weights fp32 ----------
__global__ __launch_bounds__(256) void k_prep(
    const void* __restrict__ x, const void* __restrict__ wp,
    const void* __restrict__ bp,
    const void* __restrict__ wi1, const void* __restrict__ bi1,
    const void* __restrict__ wi2, const void* __restrict__ bi2,
    const void* __restrict__ wo1, const void* __restrict__ bo1,
    const void* __restrict__ wo2, const void* __restrict__ bo2,
    const void* __restrict__ gamma, const void* __restrict__ beta,
    unsigned short* __restrict__ wpT,    // [512][768] bf16
    unsigned short* __restrict__ wo2T,   // [512][64]  bf16
    float* __restrict__ wW)
{
  const int t = threadIdx.x, b = blockIdx.x;
  const bool isb = detect_bf16((const unsigned int*)x, t);
  const int tx = t & 31, ty = t >> 5;

  if (b < 384) {
    __shared__ unsigned short tile[32][33];
    const int n0 = (b & 15) * 32, k0 = (b >> 4) * 32;
#pragma unroll
    for (int i = 0; i < 32; i += 8)
      tile[ty + i][tx] = f32_to_bf16bits(ldf(wp, (k0 + ty + i) * DOUT + n0 + tx, isb));
    __syncthreads();
#pragma unroll
    for (int i = 0; i < 32; i += 8)
      wpT[(size_t)(n0 + ty + i) * DIN + k0 + tx] = tile[tx][ty + i];
  } else if (b < 416) {
    __shared__ unsigned short tile[32][33];
    const int tb = b - 384;
    const int c0 = (tb & 15) * 32, g0 = (tb >> 4) * 32;
#pragma unroll
    for (int i = 0; i < 32; i += 8)
      tile[ty + i][tx] = f32_to_bf16bits(ldf(wo2, (g0 + ty + i) * DOUT + c0 + tx, isb));
    __syncthreads();
#pragma unroll
    for (int i = 0; i < 32; i += 8)
      wo2T[(size_t)(c0 + ty + i) * QDIM + g0 + tx] = tile[tx][ty + i];
  } else {
    for (int e = (b - 416) * 256 + t; e < W_TOT; e += 8 * 256) {
      float v;
      if      (e < W_WI1) v = ldf(bp,    e - W_BP,  isb);
      else if (e < W_BI1) v = ldf(wi1,   e - W_WI1, isb);
      else if (e < W_WI2) v = ldf(bi1,   e - W_BI1, isb);
      else if (e < W_BI2) v = ldf(wi2,   e - W_WI2, isb);
      else if (e < W_WO1) v = ldf(bi2,   e - W_BI2, isb);
      else if (e < W_BO1) v = ldf(wo1,   e - W_WO1, isb);
      else if (e < W_WO2) v = ldf(bo1,   e - W_BO1, isb);
      else if (e < W_BO2) v = ldf(wo2,   e - W_WO2, isb);
      else if (e < W_GAM) v = ldf(bo2,   e - W_BO2, isb);
      else if (e < W_BET) v = ldf(gamma, e - W_GAM, isb);
      else                v = ldf(beta,  e - W_BET, isb);
      wW[e] = v;
    }
  }
}

// ---------- kernel 2: fused GEMM + KAN tail + LN; 16 rows/block, 512 threads ----------
// 8 waves x 64 cols (4 MFMA chains each). __launch_bounds__(512,2) -> 256-VGPR
// ceiling: no spills (R10's 1024-thr/64-VGPR config spilled ~45 MB to scratch).
__global__ __launch_bounds__(512, 2) void k_main(
    const void* __restrict__ x,              // [4096][768]
    const unsigned short* __restrict__ wpT,  // [512][768] bf16
    const unsigned short* __restrict__ wo2T, // [512][64]  bf16
    const float* __restrict__ wW,
    void* __restrict__ out)
{
  // LDS map (bytes):
  //  region0 [0,33024): As ushort[16][776] (GEMM) / sXp float[16][516] (tail)
  //  sS @33024 f32[16][32]  sU @35072 f32[16][64]  sTb @39168 bf16[16][72]
  //  sRed @41472 f32[8][16][2]  sSt @42496 f32[16][2]  sW1 @42624  sB1 @42752
  __shared__ alignas(16) char smem[42880];
  unsigned short* As   = (unsigned short*)smem;
  float*          sXp  = (float*)smem;
  float*          sS   = (float*)(smem + 33024);
  float*          sU   = (float*)(smem + 35072);
  unsigned short* sTb  = (unsigned short*)(smem + 39168);
  float*          sRed = (float*)(smem + 41472);
  float*          sSt  = (float*)(smem + 42496);
  float*          sW1  = (float*)(smem + 42624);
  float*          sB1  = (float*)(smem + 42752);

  const int t    = threadIdx.x;
  const int wv   = t >> 6, lane = t & 63;
  const int lm   = lane & 15, quad = lane >> 4;
  const int b0   = blockIdx.x * 16;
  const bool isb = detect_bf16((const unsigned int*)x, t);

  // ---- stage A: 16 rows x 768 -> As bf16[16][776]; 6 chunks of 4 per thread ----
#pragma unroll
  for (int i = 0; i < 6; ++i) {
    const int c = i * 512 + t;             // 0..3071
    const int row = c / 192, off = (c - row * 192) * 4;
    unsigned short a4[4];
    if (isb) {
      *(uint2*)a4 = *(const uint2*)((const unsigned short*)x + (size_t)(b0 + row) * DIN + off);
    } else {
      const float4 f = *(const float4*)((const float*)x + (size_t)(b0 + row) * DIN + off);
      a4[0] = f32_to_bf16bits(f.x); a4[1] = f32_to_bf16bits(f.y);
      a4[2] = f32_to_bf16bits(f.z); a4[3] = f32_to_bf16bits(f.w);
    }
    *(uint2*)&As[row * 776 + off] = *(const uint2*)a4;
  }
  if (t < 32) { sW1[t] = wW[W_WI1 + t]; sB1[t] = wW[W_BI1 + t]; }

  // ---- B prefetch (kt=0,1) before the barrier; 4 chains/wave ----
  const unsigned short* wb[4];
  short8_t cur[4], nxt[4];
#pragma unroll
  for (int nt = 0; nt < 4; ++nt) {
    wb[nt] = wpT + (size_t)(wv * 64 + nt * 16 + lm) * DIN + quad * 8;
    cur[nt] = *(const short8_t*)wb[nt];
    nxt[nt] = *(const short8_t*)(wb[nt] + 32);
  }
  __syncthreads();

  // ---- K-loop: 24 iters, depth-2 prefetch, no barriers ----
  f32x4_t acc[4] = {};
#pragma unroll
  for (int kt = 0; kt < 24; ++kt) {
    short8_t fut[4];
#pragma unroll
    for (int nt = 0; nt < 4; ++nt)
      fut[nt] = *(const short8_t*)(wb[nt] + (kt + 2) * 32);  // overrun lands in wo2T (valid)
    const short8_t av = *(const short8_t*)&As[lm * 776 + kt * 32 + quad * 8];
    const bf16x8_t af = __builtin_bit_cast(bf16x8_t, av);
#pragma unroll
    for (int nt = 0; nt < 4; ++nt)
      acc[nt] = __builtin_amdgcn_mfma_f32_16x16x32_bf16(
          af, __builtin_bit_cast(bf16x8_t, cur[nt]), acc[nt], 0, 0, 0);
#pragma unroll
    for (int nt = 0; nt < 4; ++nt) { cur[nt] = nxt[nt]; nxt[nt] = fut[nt]; }
  }
  __syncthreads();   // As reads done before sXp overlays

  // ---- epilogue: C layout col=lane&15, row=quad*4+i (verified R7) ----
#pragma unroll
  for (int nt = 0; nt < 4; ++nt) {
    const int col = wv * 64 + nt * 16 + lm;
    const float bpv = wW[W_BP + col];
#pragma unroll
    for (int i = 0; i < 4; ++i)
      sXp[(quad * 4 + i) * 516 + col] = acc[nt][i] + bpv;
  }
  __syncthreads();

  // ---- phase S: 2 rows/wave; lane: cg=lane&31 -> 16 cols, hg=lane>>5 -> 16 h ----
  {
    const int cg = lane & 31, hg = lane >> 5;
#pragma unroll
    for (int half = 0; half < 2; ++half) {
      const int r = wv * 2 + half;
      const float* row = &sXp[r * 516 + cg * 16];
      float xc[16];
#pragma unroll
      for (int j = 0; j < 4; ++j) {
        const float4 v = *(const float4*)&row[j * 4];
        xc[j*4+0] = v.x; xc[j*4+1] = v.y; xc[j*4+2] = v.z; xc[j*4+3] = v.w;
      }
      float S16[16];
#pragma unroll
      for (int j = 0; j < 16; ++j) {
        const float w = sW1[hg * 16 + j], bb = sB1[hg * 16 + j];
        float a = 0.f;
#pragma unroll
        for (int c = 0; c < 16; ++c) a += fmaxf(fmaf(xc[c], w, bb), 0.f);
        S16[j] = a;
      }
#pragma unroll
      for (int off = 1; off < 32; off <<= 1)
#pragma unroll
        for (int j = 0; j < 16; ++j) S16[j] += __shfl_xor(S16[j], off);
      if (cg == 0) {
#pragma unroll
        for (int j = 0; j < 16; ++j) sS[r * 32 + hg * 16 + j] = S16[j];
      }
    }
  }
  __syncthreads();

  // ---- phase u: 2 entries/thread ----
#pragma unroll
  for (int rep = 0; rep < 2; ++rep) {
    const int e = rep * 512 + t;
    const int r = e >> 6, q = e & 63;
    float a = 0.f;
#pragma unroll
    for (int h4 = 0; h4 < 32; h4 += 4) {
      const float4 s4 = *(const float4*)&sS[r * 32 + h4];
      a = fmaf(s4.x, wW[W_WI2 + (h4 + 0) * QDIM + q], a);
      a = fmaf(s4.y, wW[W_WI2 + (h4 + 1) * QDIM + q], a);
      a = fmaf(s4.z, wW[W_WI2 + (h4 + 2) * QDIM + q], a);
      a = fmaf(s4.w, wW[W_WI2 + (h4 + 3) * QDIM + q], a);
    }
    sU[e] = a + 512.f * wW[W_BI2 + q];
  }
  __syncthreads();

  // ---- phase T: 2 entries/thread; T stored bf16 for MFMA ----
#pragma unroll
  for (int rep = 0; rep < 2; ++rep) {
    const int e = rep * 512 + t;
    const int r = e >> 6, g = e & 63;
    const float w = wW[W_WO1 + g], bb = wW[W_BO1 + g];
    float a = 0.f;
#pragma unroll
    for (int q = 0; q < QDIM; q += 4) {
      const float4 v = *(const float4*)&sU[r * 64 + q];
      a += fmaxf(fmaf(v.x, w, bb), 0.f);
      a += fmaxf(fmaf(v.y, w, bb), 0.f);
      a += fmaxf(fmaf(v.z, w, bb), 0.f);
      a += fmaxf(fmaf(v.w, w, bb), 0.f);
    }
    sTb[r * 72 + g] = f32_to_bf16bits(a);
  }
  __syncthreads();

  // ---- summed via MFMA: D[16r][64c per wave] = T[16][64] @ wo2T^T ----
  f32x4_t sa[4] = {};
#pragma unroll
  for (int kt = 0; kt < 2; ++kt) {
    const short8_t aT = *(const short8_t*)&sTb[lm * 72 + kt * 32 + quad * 8];
    const bf16x8_t aTf = __builtin_bit_cast(bf16x8_t, aT);
#pragma unroll
    for (int nt = 0; nt < 4; ++nt) {
      const short8_t bW = *(const short8_t*)
          (wo2T + (size_t)(wv * 64 + nt * 16 + lm) * QDIM + kt * 32 + quad * 8);
      sa[nt] = __builtin_amdgcn_mfma_f32_16x16x32_bf16(
          aTf, __builtin_bit_cast(bf16x8_t, bW), sa[nt], 0, 0, 0);
    }
  }
#pragma unroll
  for (int nt = 0; nt < 4; ++nt) {
    const float bz = 64.f * wW[W_BO2 + wv * 64 + nt * 16 + lm];
#pragma unroll
    for (int i = 0; i < 4; ++i) sa[nt][i] += bz;
  }

  // ---- per-row stats: butterfly over 16 lm-lanes; rows = quad*4+i ----
  {
    float pr[4], prs[4];
#pragma unroll
    for (int i = 0; i < 4; ++i) {
      float s = 0.f, s2 = 0.f;
#pragma unroll
      for (int nt = 0; nt < 4; ++nt) { s += sa[nt][i]; s2 += sa[nt][i] * sa[nt][i]; }
      pr[i] = s; prs[i] = s2;
    }
#pragma unroll
    for (int off = 1; off < 16; off <<= 1)
#pragma unroll
      for (int i = 0; i < 4; ++i) {
        pr[i]  += __shfl_xor(pr[i],  off);
        prs[i] += __shfl_xor(prs[i], off);
      }
    if (lm == 0) {
#pragma unroll
      for (int i = 0; i < 4; ++i) {
        sRed[(wv * 16 + quad * 4 + i) * 2 + 0] = pr[i];
        sRed[(wv * 16 + quad * 4 + i) * 2 + 1] = prs[i];
      }
    }
  }
  __syncthreads();
  if (t < 16) {
    float sm = 0.f, sq = 0.f;
#pragma unroll
    for (int w = 0; w < 8; ++w) {
      sm += sRed[(w * 16 + t) * 2 + 0];
      sq += sRed[(w * 16 + t) * 2 + 1];
    }
    const float mu  = sm * (1.f / 512.f);
    const float var = fmaxf(sq * (1.f / 512.f) - mu * mu, 0.f);
    sSt[t * 2 + 0] = mu;
    sSt[t * 2 + 1] = rsqrtf(var + 1e-5f);
  }
  __syncthreads();

  // ---- LN + store from D-regs ----
#pragma unroll
  for (int nt = 0; nt < 4; ++nt) {
    const int col = wv * 64 + nt * 16 + lm;
    const float gm = wW[W_GAM + col], bt = wW[W_BET + col];
#pragma unroll
    for (int i = 0; i < 4; ++i) {
      const int r = quad * 4 + i;
      const float o = (sa[nt][i] - sSt[r * 2 + 0]) * sSt[r * 2 + 1] * gm + bt;
      if (isb)
        ((unsigned short*)out)[(size_t)(b0 + r) * DOUT + col] = f32_to_bf16bits(o);
      else
        ((float*)out)[(size_t)(b0 + r) * DOUT + col] = o;
    }
  }
}

extern "C" void kernel_launch(void* const* d_in, const int* in_sizes, int n_in,
                              void* d_out, int out_size, void* d_ws, size_t ws_size,
                              hipStream_t stream) {
  char* ws = (char*)d_ws;
  unsigned short* wpT  = (unsigned short*)(ws + WS_WPT);
  unsigned short* wo2T = (unsigned short*)(ws + WS_WO2T);
  float*          wW   = (float*)(ws + WS_WW);

  k_prep<<<424, 256, 0, stream>>>(d_in[0], d_in[1], d_in[2], d_in[3], d_in[4],
                                  d_in[5], d_in[6], d_in[7], d_in[8], d_in[9],
                                  d_in[10], d_in[11], d_in[12], wpT, wo2T, wW);
  k_main<<<B_ROWS / 16, 512, 0, stream>>>(d_in[0], wpT, wo2T, wW, d_out);
}

// Round 12
// 113.696 us; speedup vs baseline: 1.2013x; 1.1414x over previous
//
#include <hip/hip_runtime.h>
#include <hip/hip_bf16.h>

#define B_ROWS 4096
#define DIN    768
#define DOUT   512
#define QDIM   64
#define H1C    32
#define H2C    64

// canonical fp32 weight block offsets (floats)
#define W_BP    0
#define W_WI1   512
#define W_BI1   544
#define W_WI2   576
#define W_BI2   2624
#define W_WO1   2688
#define W_BO1   2752
#define W_WO2   2816
#define W_BO2   35584
#define W_GAM   36096
#define W_BET   36608
#define W_TOT   37120

// ws layout (bytes). wpB = MFMA-native fragments [24 kt][32 ntile][64 lane][8 bf16]
// wo2B right after absorbs the K-loop depth-2 prefetch overrun (<= 64 KB).
#define WS_WPB  0          // 24*32*64*16 = 786432
#define WS_WO2B 786432     // 2*32*64*16  =  65536
#define WS_WW   851968     // 37120*4

typedef short  short8_t  __attribute__((ext_vector_type(8)));
typedef __bf16 bf16x8_t  __attribute__((ext_vector_type(8)));
typedef float  f32x4_t   __attribute__((ext_vector_type(4)));

__device__ __forceinline__ float bf16bits_to_f32(unsigned short u) {
  return __builtin_bit_cast(float, ((unsigned int)u) << 16);
}
__device__ __forceinline__ unsigned short f32_to_bf16bits(float f) {
  return __builtin_bit_cast(unsigned short, __float2bfloat16(f));
}
__device__ __forceinline__ float ldf(const void* p, int i, bool isb) {
  if (isb) return bf16bits_to_f32(((const unsigned short*)p)[i]);
  return ((const float*)p)[i];
}
// per-wave dtype detect from x's first 64 words (verified: picks fp32 here)
__device__ __forceinline__ bool detect_bf16(const unsigned int* xw, int t) {
  const unsigned int w = xw[t & 63];
  const unsigned int e = (w >> 7) & 0xffu;
  const bool hit = (e >= 118u && e <= 127u);
  return __popcll(__ballot(hit)) >= 40;
}

// ---------- kernel 1: prep — wpB/wo2B in MFMA-native fragment layout, wW fp32 ----------
// Fragment (tile kt/gt, ntile, lane): n = ntile*16 + (lane&15),
// k = kt*32 + (lane>>4)*8 + j, j=0..7 — exactly the 16x16x32 B-operand layout.
__global__ __launch_bounds__(256) void k_prep(
    const void* __restrict__ x, const void* __restrict__ wp,
    const void* __restrict__ bp,
    const void* __restrict__ wi1, const void* __restrict__ bi1,
    const void* __restrict__ wi2, const void* __restrict__ bi2,
    const void* __restrict__ wo1, const void* __restrict__ bo1,
    const void* __restrict__ wo2, const void* __restrict__ bo2,
    const void* __restrict__ gamma, const void* __restrict__ beta,
    unsigned short* __restrict__ wpB,    // [24][32][64][8] bf16
    unsigned short* __restrict__ wo2B,   // [2][32][64][8]  bf16
    float* __restrict__ wW)
{
  const int t = threadIdx.x, b = blockIdx.x;
  const bool isb = detect_bf16((const unsigned int*)x, t);

  if (b < 192) {
    // wpB: 49152 fragments, one per thread
    const int e     = b * 256 + t;
    const int kt    = e >> 11;          // 0..23
    const int rem   = e & 2047;
    const int ntile = rem >> 6, lane = rem & 63;
    const int n  = ntile * 16 + (lane & 15);
    const int kb = kt * 32 + (lane >> 4) * 8;
    unsigned short f[8];
#pragma unroll
    for (int j = 0; j < 8; ++j)
      f[j] = f32_to_bf16bits(ldf(wp, (kb + j) * DOUT + n, isb));
    *(short8_t*)&wpB[(size_t)e * 8] = *(const short8_t*)f;
  } else if (b < 208) {
    // wo2B: 4096 fragments (B[n=c][k=g] = wo2[g][c])
    const int e     = (b - 192) * 256 + t;
    const int gt    = e >> 11;          // 0..1
    const int rem   = e & 2047;
    const int ctile = rem >> 6, lane = rem & 63;
    const int c  = ctile * 16 + (lane & 15);
    const int gb = gt * 32 + (lane >> 4) * 8;
    unsigned short f[8];
#pragma unroll
    for (int j = 0; j < 8; ++j)
      f[j] = f32_to_bf16bits(ldf(wo2, (gb + j) * DOUT + c, isb));
    *(short8_t*)&wo2B[(size_t)e * 8] = *(const short8_t*)f;
  } else {
    for (int e = (b - 208) * 256 + t; e < W_TOT; e += 8 * 256) {
      float v;
      if      (e < W_WI1) v = ldf(bp,    e - W_BP,  isb);
      else if (e < W_BI1) v = ldf(wi1,   e - W_WI1, isb);
      else if (e < W_WI2) v = ldf(bi1,   e - W_BI1, isb);
      else if (e < W_BI2) v = ldf(wi2,   e - W_WI2, isb);
      else if (e < W_WO1) v = ldf(bi2,   e - W_BI2, isb);
      else if (e < W_BO1) v = ldf(wo1,   e - W_WO1, isb);
      else if (e < W_WO2) v = ldf(bo1,   e - W_BO1, isb);
      else if (e < W_BO2) v = ldf(wo2,   e - W_WO2, isb);
      else if (e < W_GAM) v = ldf(bo2,   e - W_BO2, isb);
      else if (e < W_BET) v = ldf(gamma, e - W_GAM, isb);
      else                v = ldf(beta,  e - W_BET, isb);
      wW[e] = v;
    }
  }
}

// ---------- kernel 2: fused GEMM + KAN tail + LN; 16 rows/block, 512 threads ----------
// B-loads now fully coalesced (1024 B/wave/fragment = 16 lines, was 64).
__global__ __launch_bounds__(512, 2) void k_main(
    const void* __restrict__ x,              // [4096][768]
    const unsigned short* __restrict__ wpB,  // native fragments
    const unsigned short* __restrict__ wo2B, // native fragments
    const float* __restrict__ wW,
    void* __restrict__ out)
{
  __shared__ alignas(16) char smem[42880];
  unsigned short* As   = (unsigned short*)smem;        // [16][776] bf16 (GEMM)
  float*          sXp  = (float*)smem;                 // [16][516] f32 (tail)
  float*          sS   = (float*)(smem + 33024);
  float*          sU   = (float*)(smem + 35072);
  unsigned short* sTb  = (unsigned short*)(smem + 39168);
  float*          sRed = (float*)(smem + 41472);
  float*          sSt  = (float*)(smem + 42496);
  float*          sW1  = (float*)(smem + 42624);
  float*          sB1  = (float*)(smem + 42752);

  const int t    = threadIdx.x;
  const int wv   = t >> 6, lane = t & 63;
  const int lm   = lane & 15, quad = lane >> 4;
  const int b0   = blockIdx.x * 16;
  const bool isb = detect_bf16((const unsigned int*)x, t);

  // ---- stage A: 16 rows x 768 -> As bf16[16][776] ----
#pragma unroll
  for (int i = 0; i < 6; ++i) {
    const int c = i * 512 + t;
    const int row = c / 192, off = (c - row * 192) * 4;
    unsigned short a4[4];
    if (isb) {
      *(uint2*)a4 = *(const uint2*)((const unsigned short*)x + (size_t)(b0 + row) * DIN + off);
    } else {
      const float4 f = *(const float4*)((const float*)x + (size_t)(b0 + row) * DIN + off);
      a4[0] = f32_to_bf16bits(f.x); a4[1] = f32_to_bf16bits(f.y);
      a4[2] = f32_to_bf16bits(f.z); a4[3] = f32_to_bf16bits(f.w);
    }
    *(uint2*)&As[row * 776 + off] = *(const uint2*)a4;
  }
  if (t < 32) { sW1[t] = wW[W_WI1 + t]; sB1[t] = wW[W_BI1 + t]; }

  // ---- B prefetch (kt=0,1); stream nt: fragments at (kt*32 + wv*4+nt)*1024 B ----
  const unsigned short* wbase[4];
  short8_t cur[4], nxt[4];
#pragma unroll
  for (int nt = 0; nt < 4; ++nt) {
    wbase[nt] = wpB + ((size_t)(wv * 4 + nt) * 64 + lane) * 8;
    cur[nt] = *(const short8_t*)wbase[nt];
    nxt[nt] = *(const short8_t*)(wbase[nt] + 16384);   // +32*64*8 shorts per kt
  }
  __syncthreads();

  // ---- K-loop: 24 iters, depth-2 prefetch, coalesced B, no barriers ----
  f32x4_t acc[4] = {};
#pragma unroll
  for (int kt = 0; kt < 24; ++kt) {
    short8_t fut[4];
#pragma unroll
    for (int nt = 0; nt < 4; ++nt)
      fut[nt] = *(const short8_t*)(wbase[nt] + (size_t)(kt + 2) * 16384);  // overrun -> wo2B (valid)
    const short8_t av = *(const short8_t*)&As[lm * 776 + kt * 32 + quad * 8];
    const bf16x8_t af = __builtin_bit_cast(bf16x8_t, av);
#pragma unroll
    for (int nt = 0; nt < 4; ++nt)
      acc[nt] = __builtin_amdgcn_mfma_f32_16x16x32_bf16(
          af, __builtin_bit_cast(bf16x8_t, cur[nt]), acc[nt], 0, 0, 0);
#pragma unroll
    for (int nt = 0; nt < 4; ++nt) { cur[nt] = nxt[nt]; nxt[nt] = fut[nt]; }
  }
  __syncthreads();

  // ---- epilogue: C layout col=lane&15, row=quad*4+i (verified R7) ----
#pragma unroll
  for (int nt = 0; nt < 4; ++nt) {
    const int col = (wv * 4 + nt) * 16 + lm;
    const float bpv = wW[W_BP + col];
#pragma unroll
    for (int i = 0; i < 4; ++i)
      sXp[(quad * 4 + i) * 516 + col] = acc[nt][i] + bpv;
  }
  __syncthreads();

  // ---- phase S: 2 rows/wave; lane: cg -> 16 cols, hg -> 16 h ----
  {
    const int cg = lane & 31, hg = lane >> 5;
#pragma unroll
    for (int half = 0; half < 2; ++half) {
      const int r = wv * 2 + half;
      const float* row = &sXp[r * 516 + cg * 16];
      float xc[16];
#pragma unroll
      for (int j = 0; j < 4; ++j) {
        const float4 v = *(const float4*)&row[j * 4];
        xc[j*4+0] = v.x; xc[j*4+1] = v.y; xc[j*4+2] = v.z; xc[j*4+3] = v.w;
      }
      float S16[16];
#pragma unroll
      for (int j = 0; j < 16; ++j) {
        const float w = sW1[hg * 16 + j], bb = sB1[hg * 16 + j];
        float a = 0.f;
#pragma unroll
        for (int c = 0; c < 16; ++c) a += fmaxf(fmaf(xc[c], w, bb), 0.f);
        S16[j] = a;
      }
#pragma unroll
      for (int off = 1; off < 32; off <<= 1)
#pragma unroll
        for (int j = 0; j < 16; ++j) S16[j] += __shfl_xor(S16[j], off);
      if (cg == 0) {
#pragma unroll
        for (int j = 0; j < 16; ++j) sS[r * 32 + hg * 16 + j] = S16[j];
      }
    }
  }
  __syncthreads();

  // ---- phase u ----
#pragma unroll
  for (int rep = 0; rep < 2; ++rep) {
    const int e = rep * 512 + t;
    const int r = e >> 6, q = e & 63;
    float a = 0.f;
#pragma unroll
    for (int h4 = 0; h4 < 32; h4 += 4) {
      const float4 s4 = *(const float4*)&sS[r * 32 + h4];
      a = fmaf(s4.x, wW[W_WI2 + (h4 + 0) * QDIM + q], a);
      a = fmaf(s4.y, wW[W_WI2 + (h4 + 1) * QDIM + q], a);
      a = fmaf(s4.z, wW[W_WI2 + (h4 + 2) * QDIM + q], a);
      a = fmaf(s4.w, wW[W_WI2 + (h4 + 3) * QDIM + q], a);
    }
    sU[e] = a + 512.f * wW[W_BI2 + q];
  }
  __syncthreads();

  // ---- phase T (bf16 for MFMA) ----
#pragma unroll
  for (int rep = 0; rep < 2; ++rep) {
    const int e = rep * 512 + t;
    const int r = e >> 6, g = e & 63;
    const float w = wW[W_WO1 + g], bb = wW[W_BO1 + g];
    float a = 0.f;
#pragma unroll
    for (int q = 0; q < QDIM; q += 4) {
      const float4 v = *(const float4*)&sU[r * 64 + q];
      a += fmaxf(fmaf(v.x, w, bb), 0.f);
      a += fmaxf(fmaf(v.y, w, bb), 0.f);
      a += fmaxf(fmaf(v.z, w, bb), 0.f);
      a += fmaxf(fmaf(v.w, w, bb), 0.f);
    }
    sTb[r * 72 + g] = f32_to_bf16bits(a);
  }
  __syncthreads();

  // ---- summed via MFMA: native wo2B fragments, coalesced ----
  f32x4_t sa[4] = {};
#pragma unroll
  for (int kt = 0; kt < 2; ++kt) {
    const short8_t aT = *(const short8_t*)&sTb[lm * 72 + kt * 32 + quad * 8];
    const bf16x8_t aTf = __builtin_bit_cast(bf16x8_t, aT);
#pragma unroll
    for (int nt = 0; nt < 4; ++nt) {
      const short8_t bW = *(const short8_t*)
          (wo2B + (((size_t)kt * 32 + wv * 4 + nt) * 64 + lane) * 8);
      sa[nt] = __builtin_amdgcn_mfma_f32_16x16x32_bf16(
          aTf, __builtin_bit_cast(bf16x8_t, bW), sa[nt], 0, 0, 0);
    }
  }
#pragma unroll
  for (int nt = 0; nt < 4; ++nt) {
    const float bz = 64.f * wW[W_BO2 + (wv * 4 + nt) * 16 + lm];
#pragma unroll
    for (int i = 0; i < 4; ++i) sa[nt][i] += bz;
  }

  // ---- per-row stats ----
  {
    float pr[4], prs[4];
#pragma unroll
    for (int i = 0; i < 4; ++i) {
      float s = 0.f, s2 = 0.f;
#pragma unroll
      for (int nt = 0; nt < 4; ++nt) { s += sa[nt][i]; s2 += sa[nt][i] * sa[nt][i]; }
      pr[i] = s; prs[i] = s2;
    }
#pragma unroll
    for (int off = 1; off < 16; off <<= 1)
#pragma unroll
      for (int i = 0; i < 4; ++i) {
        pr[i]  += __shfl_xor(pr[i],  off);
        prs[i] += __shfl_xor(prs[i], off);
      }
    if (lm == 0) {
#pragma unroll
      for (int i = 0; i < 4; ++i) {
        sRed[(wv * 16 + quad * 4 + i) * 2 + 0] = pr[i];
        sRed[(wv * 16 + quad * 4 + i) * 2 + 1] = prs[i];
      }
    }
  }
  __syncthreads();
  if (t < 16) {
    float sm = 0.f, sq = 0.f;
#pragma unroll
    for (int w = 0; w < 8; ++w) {
      sm += sRed[(w * 16 + t) * 2 + 0];
      sq += sRed[(w * 16 + t) * 2 + 1];
    }
    const float mu  = sm * (1.f / 512.f);
    const float var = fmaxf(sq * (1.f / 512.f) - mu * mu, 0.f);
    sSt[t * 2 + 0] = mu;
    sSt[t * 2 + 1] = rsqrtf(var + 1e-5f);
  }
  __syncthreads();

  // ---- LN + store ----
#pragma unroll
  for (int nt = 0; nt < 4; ++nt) {
    const int col = (wv * 4 + nt) * 16 + lm;
    const float gm = wW[W_GAM + col], bt = wW[W_BET + col];
#pragma unroll
    for (int i = 0; i < 4; ++i) {
      const int r = quad * 4 + i;
      const float o = (sa[nt][i] - sSt[r * 2 + 0]) * sSt[r * 2 + 1] * gm + bt;
      if (isb)
        ((unsigned short*)out)[(size_t)(b0 + r) * DOUT + col] = f32_to_bf16bits(o);
      else
        ((float*)out)[(size_t)(b0 + r) * DOUT + col] = o;
    }
  }
}

extern "C" void kernel_launch(void* const* d_in, const int* in_sizes, int n_in,
                              void* d_out, int out_size, void* d_ws, size_t ws_size,
                              hipStream_t stream) {
  char* ws = (char*)d_ws;
  unsigned short* wpB  = (unsigned short*)(ws + WS_WPB);
  unsigned short* wo2B = (unsigned short*)(ws + WS_WO2B);
  float*          wW   = (float*)(ws + WS_WW);

  k_prep<<<216, 256, 0, stream>>>(d_in[0], d_in[1], d_in[2], d_in[3], d_in[4],
                                  d_in[5], d_in[6], d_in[7], d_in[8], d_in[9],
                                  d_in[10], d_in[11], d_in[12], wpB, wo2B, wW);
  k_main<<<B_ROWS / 16, 512, 0, stream>>>(d_in[0], wpB, wo2B, wW, d_out);
}